// Round 1
// 703.060 us; speedup vs baseline: 1.6511x; 1.6511x over previous
//
#include <hip/hip_runtime.h>
#include <math.h>

// ---------------------------------------------------------------------------
// MACE layer, round 7: radial MLP moved to MFMA (f16), TP split into its own
// memory-bound kernel.
//  - k_frag: pre-packs W1..W4 into fragment-native fp16 tables (60 frags,
//    fold 1/sqrt(R) and 1/sqrt(H) scales into weights).
//  - k_mlp: per wave, 2 x 16-edge tiles through L1..L4 via
//    mfma_f32_16x16x32_f16; inter-layer transpose via wave-private
//    XOR-swizzled LDS (no barriers). Writes w[E,320] fp16 in CSR order.
//  - k_tp: 4 threads/edge; reads w, gathers fp16 s_up/v_up, computes the
//    5-path tensor product, overwrites w buffer in place with bf16 messages
//    (component c lands where path p=c was, after consumption).
//  - k_gather: row stride 256 -> 320 (rest identical). k_post unchanged.
//
// Workspace (floats, ~135.6 MB — under the previous 135.63 MB footprint):
//   s_up   [N*64  f16]  @ 0          (1,048,576 f)
//   v_up   [N*192 f16]  @ 1048576    (3,145,728 f)
//   acc    [N*256 f32]  @ 4194304    (8,388,608 f, zeroed per call)
//   fragw  [30720 f16]  @ 12582912   (16,384 f slot)
//   row_st [32772 int]  @ 12599296
//   cursor [32768 int]  @ 12632068
//   elist  [262144 int] @ 12664836
//   wm     [EC*320 f16] @ 12926980   (83.9 MB; doubles as m_buf, bf16)
// ---------------------------------------------------------------------------

#define NN 32768
#define EE 262144
#define EC 131072                        // edges per chunk (2 chunks)
#define INV8 0.125f                      // 1/sqrt(64)
#define INV_SQRT8 0.35355339059327373f   // 1/sqrt(8)
#define INVZ 0.039528470752104741f       // 1/sqrt(64*10)
#define EPS_C 0.25f
#define RS2 0.70710678118654752f         // 1/sqrt(2)

typedef _Float16 f16;
typedef f16 f16x8 __attribute__((ext_vector_type(8)));
typedef float f32x4 __attribute__((ext_vector_type(4)));

__device__ __forceinline__ unsigned bfpair(float lo, float hi) {
  unsigned ul = __float_as_uint(lo);
  unsigned uh = __float_as_uint(hi);
  ul = (ul + 0x7FFFu + ((ul >> 16) & 1u)) >> 16;
  uh = (uh + 0x7FFFu + ((uh >> 16) & 1u)) >> 16;
  return ul | (uh << 16);
}

__device__ __forceinline__ unsigned short f2h(float x) {
  union { f16 h; unsigned short u; } cv;
  cv.h = (f16)x;
  return cv.u;
}

__device__ __forceinline__ f16x8 pack8(float4 a, float4 b) {
  f16x8 r;
  r[0] = (f16)a.x; r[1] = (f16)a.y; r[2] = (f16)a.z; r[3] = (f16)a.w;
  r[4] = (f16)b.x; r[5] = (f16)b.y; r[6] = (f16)b.z; r[7] = (f16)b.w;
  return r;
}

__device__ __forceinline__ float silu_f(float x) {
  return x / (1.0f + __expf(-x));
}

// ---------------------------------------------------------------------------
// Weight fragment packing. 60 fragments x 64 lanes x 8 f16 (16B per lane).
// Fragment (layer, t, ks): lane l holds W[k = ks*32 + 8*(l>>4) + i]
//                                        [j = t*16 + (l&15)], i = 0..7.
// Bases: L1 @0 (4 frags, K=8 zero-padded), L2 @4 (8), L3 @12 (8), L4 @20 (40).
// Scales folded: L1 *= 1/sqrt(8); L2,L3,L4 *= 1/8.
// ---------------------------------------------------------------------------
__global__ __launch_bounds__(256) void k_frag(
    const float* __restrict__ W1, const float* __restrict__ W2,
    const float* __restrict__ W3, const float* __restrict__ W4,
    unsigned short* __restrict__ fragw) {
  int id = blockIdx.x * 256 + threadIdx.x;
  if (id >= 3840) return;
  int fid = id >> 6, lane = id & 63;
  int q = lane >> 4, c = lane & 15;
  const float* W; int K, N, t, ks; float sc;
  if (fid < 4)       { W = W1; K = 8;  N = 64;  t = fid;            ks = 0;             sc = INV_SQRT8; }
  else if (fid < 12) { W = W2; K = 64; N = 64;  t = (fid - 4) >> 1; ks = (fid - 4) & 1; sc = INV8; }
  else if (fid < 20) { W = W3; K = 64; N = 64;  t = (fid - 12) >> 1; ks = (fid - 12) & 1; sc = INV8; }
  else               { W = W4; K = 64; N = 320; t = (fid - 20) >> 1; ks = (fid - 20) & 1; sc = INV8; }
  unsigned short o[8];
#pragma unroll
  for (int i = 0; i < 8; ++i) {
    int k = ks * 32 + 8 * q + i;
    float v = (k < K) ? W[k * N + t * 16 + c] * sc : 0.0f;
    o[i] = f2h(v);
  }
  *(uint4*)(fragw + (size_t)id * 8) = *(const uint4*)o;
}

__global__ __launch_bounds__(256) void k_hist(const int* __restrict__ rcv,
                                              int* __restrict__ cnt) {
  int e = blockIdx.x * 256 + threadIdx.x;
  atomicAdd(&cnt[rcv[e]], 1);
}

__global__ __launch_bounds__(1024) void k_scan(const int* __restrict__ cnt,
                                               int* __restrict__ row_start,
                                               int* __restrict__ cursor) {
  __shared__ int tot[1024];
  int t = threadIdx.x;
  int base = t * 32;
  int local[32];
  int s = 0;
#pragma unroll
  for (int i = 0; i < 32; ++i) { local[i] = s; s += cnt[base + i]; }
  tot[t] = s;
  __syncthreads();
  for (int off = 1; off < 1024; off <<= 1) {
    int v = (t >= off) ? tot[t - off] : 0;
    __syncthreads();
    tot[t] += v;
    __syncthreads();
  }
  int prefix = (t == 0) ? 0 : tot[t - 1];
#pragma unroll
  for (int i = 0; i < 32; ++i) {
    int v = prefix + local[i];
    row_start[base + i] = v;
    cursor[base + i] = v;
  }
  if (t == 1023) row_start[NN] = prefix + s;
}

__global__ __launch_bounds__(256) void k_fill(const int* __restrict__ rcv,
                                              int* __restrict__ cursor,
                                              int* __restrict__ elist) {
  int e = blockIdx.x * 256 + threadIdx.x;
  int pos = atomicAdd(&cursor[rcv[e]], 1);
  elist[pos] = e;
}

// linear_up: lane g = output channel; 4 nodes per wave; fp16 outputs.
__global__ __launch_bounds__(256) void k_up(
    const float* __restrict__ nf,
    const float* __restrict__ Wups, const float* __restrict__ Wupv,
    unsigned short* __restrict__ s_up, unsigned short* __restrict__ v_up) {
  int g = threadIdx.x & 63;
  int n0 = (blockIdx.x * 4 + (threadIdx.x >> 6)) * 4;
  float su[4] = {0.f, 0.f, 0.f, 0.f};
  float vu[4][3] = {{0,0,0},{0,0,0},{0,0,0},{0,0,0}};
  for (int fq = 0; fq < 16; ++fq) {
    int f = fq * 4;
    float ws0 = Wups[(f + 0) * 64 + g], ws1 = Wups[(f + 1) * 64 + g];
    float ws2 = Wups[(f + 2) * 64 + g], ws3 = Wups[(f + 3) * 64 + g];
    float wv0 = Wupv[(f + 0) * 64 + g], wv1 = Wupv[(f + 1) * 64 + g];
    float wv2 = Wupv[(f + 2) * 64 + g], wv3 = Wupv[(f + 3) * 64 + g];
#pragma unroll
    for (int i = 0; i < 4; ++i) {
      const float* row = nf + (size_t)(n0 + i) * 256;
      float4 s4 = *(const float4*)(row + f);
      const float4* vr = (const float4*)(row + 64 + fq * 12);
      float4 va = vr[0], vb = vr[1], vc = vr[2];
      su[i]    += s4.x * ws0 + s4.y * ws1 + s4.z * ws2 + s4.w * ws3;
      vu[i][0] += va.x * wv0 + va.w * wv1 + vb.z * wv2 + vc.y * wv3;
      vu[i][1] += va.y * wv0 + vb.x * wv1 + vb.w * wv2 + vc.z * wv3;
      vu[i][2] += va.z * wv0 + vb.y * wv1 + vc.x * wv2 + vc.w * wv3;
    }
  }
#pragma unroll
  for (int i = 0; i < 4; ++i) {
    int n = n0 + i;
    s_up[n * 64 + g] = f2h(su[i] * INV8);
    v_up[(n * 3 + 0) * 64 + g] = f2h(vu[i][0] * INV8);
    v_up[(n * 3 + 1) * 64 + g] = f2h(vu[i][1] * INV8);
    v_up[(n * 3 + 2) * 64 + g] = f2h(vu[i][2] * INV8);
  }
}

// ---------------------------------------------------------------------------
// Radial MLP via MFMA. Wave = 2 M-tiles of 16 edges (CSR order), 4 waves per
// block (128 edges). Inter-layer staging in wave-private LDS, XOR-swizzled:
//   addr(row, col) = row*68 + (col ^ ((row&3)<<3))   (row=edge, col=channel)
// Writes stay 2-way banked (free); fragment reads stay a single aligned
// ds_read_b128 per 8 channels and spread across all banks.
// ---------------------------------------------------------------------------
__global__ __launch_bounds__(256) void k_mlp(
    const float* __restrict__ re, const int* __restrict__ elist,
    const unsigned short* __restrict__ fragw,
    unsigned short* __restrict__ wm, int ip0) {
  __shared__ float hs[4][2][1088];  // [wave][mtile][16 rows * 68]
  int lane = threadIdx.x & 63;
  int wv = threadIdx.x >> 6;
  int q = lane >> 4, c = lane & 15;
  int ipb = ip0 + (blockIdx.x * 4 + wv) * 32;
  float* hw0 = hs[wv][0];
  float* hw1 = hs[wv][1];
  const f32x4 zero4 = {0.f, 0.f, 0.f, 0.f};

  // ---- layer 1: A = radial embeddings (K=8, zero-padded to 32) ----
  f16x8 a1[2];
#pragma unroll
  for (int m = 0; m < 2; ++m) {
    f16x8 v = {0, 0, 0, 0, 0, 0, 0, 0};
    if (q == 0) {
      int e = elist[ipb + m * 16 + c];
      const float4* rp = (const float4*)(re + (size_t)e * 8);
      v = pack8(rp[0], rp[1]);
    }
    a1[m] = v;
  }
  {
    f32x4 acc[2][4];
#pragma unroll
    for (int t = 0; t < 4; ++t) {
      f16x8 b = *(const f16x8*)(fragw + (size_t)t * 512 + lane * 8);
#pragma unroll
      for (int m = 0; m < 2; ++m)
        acc[m][t] = __builtin_amdgcn_mfma_f32_16x16x32_f16(a1[m], b, zero4, 0, 0, 0);
    }
#pragma unroll
    for (int m = 0; m < 2; ++m) {
      float* hw = (m == 0) ? hw0 : hw1;
#pragma unroll
      for (int t = 0; t < 4; ++t)
#pragma unroll
        for (int r = 0; r < 4; ++r) {
          float x = silu_f(acc[m][t][r]);
          hw[(4 * q + r) * 68 + ((16 * t + c) ^ (r << 3))] = x;
        }
    }
  }

  // ---- layers 2 and 3 (identical structure, bases 4 and 12) ----
#pragma unroll
  for (int L = 0; L < 2; ++L) {
    int base = 4 + 8 * L;
    f16x8 af[2][2];
#pragma unroll
    for (int m = 0; m < 2; ++m) {
      const float* hw = (m == 0) ? hw0 : hw1;
#pragma unroll
      for (int ks = 0; ks < 2; ++ks) {
        const float* hp = hw + c * 68 + ks * 32 + 8 * (q ^ (c & 3));
        af[m][ks] = pack8(*(const float4*)hp, *(const float4*)(hp + 4));
      }
    }
    f32x4 acc[2][4];
#pragma unroll
    for (int t = 0; t < 4; ++t)
#pragma unroll
      for (int ks = 0; ks < 2; ++ks) {
        f16x8 b = *(const f16x8*)(fragw + (size_t)(base + t * 2 + ks) * 512 + lane * 8);
#pragma unroll
        for (int m = 0; m < 2; ++m)
          acc[m][t] = __builtin_amdgcn_mfma_f32_16x16x32_f16(
              af[m][ks], b, ks ? acc[m][t] : zero4, 0, 0, 0);
      }
#pragma unroll
    for (int m = 0; m < 2; ++m) {
      float* hw = (m == 0) ? hw0 : hw1;
#pragma unroll
      for (int t = 0; t < 4; ++t)
#pragma unroll
        for (int r = 0; r < 4; ++r) {
          float x = silu_f(acc[m][t][r]);
          hw[(4 * q + r) * 68 + ((16 * t + c) ^ (r << 3))] = x;
        }
    }
  }

  // ---- layer 4: 64 -> 320, no activation; store w (fp16) per N-tile ----
  {
    f16x8 a4[2][2];
#pragma unroll
    for (int m = 0; m < 2; ++m) {
      const float* hw = (m == 0) ? hw0 : hw1;
#pragma unroll
      for (int ks = 0; ks < 2; ++ks) {
        const float* hp = hw + c * 68 + ks * 32 + 8 * (q ^ (c & 3));
        a4[m][ks] = pack8(*(const float4*)hp, *(const float4*)(hp + 4));
      }
    }
    size_t orow = (size_t)(ipb - ip0);
#pragma unroll
    for (int t = 0; t < 20; ++t) {
      f32x4 o[2];
#pragma unroll
      for (int ks = 0; ks < 2; ++ks) {
        f16x8 b = *(const f16x8*)(fragw + (size_t)(20 + t * 2 + ks) * 512 + lane * 8);
#pragma unroll
        for (int m = 0; m < 2; ++m)
          o[m] = __builtin_amdgcn_mfma_f32_16x16x32_f16(
              a4[m][ks], b, ks ? o[m] : zero4, 0, 0, 0);
      }
#pragma unroll
      for (int m = 0; m < 2; ++m)
#pragma unroll
        for (int r = 0; r < 4; ++r)
          wm[(orow + m * 16 + 4 * q + r) * 320 + t * 16 + c] = f2h(o[m][r]);
    }
  }
}

// ---------------------------------------------------------------------------
// Tensor product. 4 threads per edge (sub = channel-block pair), CSR order.
// Reads w row (fp16), gathers fp16 sender features, overwrites the w buffer
// in place with bf16 messages: component c at offset c*64+fb*8 replaces path
// p=c (already consumed); path p=4 slice stays as dead data.
// ---------------------------------------------------------------------------
__global__ __launch_bounds__(256) void k_tp(
    const float* __restrict__ vecs,
    const unsigned short* __restrict__ s_up,
    const unsigned short* __restrict__ v_up,
    const int* __restrict__ snd, const int* __restrict__ elist,
    unsigned short* __restrict__ wm, int e0) {
  int gid = blockIdx.x * 256 + threadIdx.x;
  int ip = gid >> 2, sub = gid & 3;
  int e = elist[e0 + ip];
  float ex = vecs[(size_t)e * 3 + 0];
  float ey = vecs[(size_t)e * 3 + 1];
  float ez = vecs[(size_t)e * 3 + 2];
  int se = snd[e];
  float rn = 1.0f / (sqrtf(ex * ex + ey * ey + ez * ez) + 1e-9f);
  float Yx = ex * rn, Yy = ey * rn, Yz = ez * rn;
  const unsigned short* srow = s_up + (size_t)se * 64;
  const unsigned short* vrow = v_up + (size_t)se * 192;
  unsigned short* wrow = wm + (size_t)ip * 320;
#pragma unroll 1
  for (int fb = sub * 2; fb < sub * 2 + 2; ++fb) {
    float w[5][8];
#pragma unroll
    for (int p = 0; p < 5; ++p) {
      f16x8 h = *(const f16x8*)(wrow + p * 64 + fb * 8);
#pragma unroll
      for (int j = 0; j < 8; ++j) w[p][j] = (float)h[j];
    }
    f16x8 hss = *(const f16x8*)(srow + fb * 8);
    f16x8 hvx = *(const f16x8*)(vrow + fb * 8);
    f16x8 hvy = *(const f16x8*)(vrow + 64 + fb * 8);
    f16x8 hvz = *(const f16x8*)(vrow + 128 + fb * 8);
    float ms[8], mx[8], my[8], mz[8];
#pragma unroll
    for (int j = 0; j < 8; ++j) {
      float ssj = (float)hss[j];
      float vvx = (float)hvx[j], vvy = (float)hvy[j], vvz = (float)hvz[j];
      float dt = vvx * Yx + vvy * Yy + vvz * Yz;
      float cx = vvy * Yz - vvz * Yy;
      float cy = vvz * Yx - vvx * Yz;
      float cz = vvx * Yy - vvy * Yx;
      ms[j] = EPS_C * (w[0][j] * ssj + w[3][j] * dt);
      mx[j] = EPS_C * (w[1][j] * Yx + w[2][j] * vvx + w[4][j] * (cx * RS2));
      my[j] = EPS_C * (w[1][j] * Yy + w[2][j] * vvy + w[4][j] * (cy * RS2));
      mz[j] = EPS_C * (w[1][j] * Yz + w[2][j] * vvz + w[4][j] * (cz * RS2));
    }
    uint4 pk;
    pk.x = bfpair(ms[0], ms[1]); pk.y = bfpair(ms[2], ms[3]);
    pk.z = bfpair(ms[4], ms[5]); pk.w = bfpair(ms[6], ms[7]);
    *(uint4*)(wrow + fb * 8) = pk;
    pk.x = bfpair(mx[0], mx[1]); pk.y = bfpair(mx[2], mx[3]);
    pk.z = bfpair(mx[4], mx[5]); pk.w = bfpair(mx[6], mx[7]);
    *(uint4*)(wrow + 64 + fb * 8) = pk;
    pk.x = bfpair(my[0], my[1]); pk.y = bfpair(my[2], my[3]);
    pk.z = bfpair(my[4], my[5]); pk.w = bfpair(my[6], my[7]);
    *(uint4*)(wrow + 128 + fb * 8) = pk;
    pk.x = bfpair(mz[0], mz[1]); pk.y = bfpair(mz[2], mz[3]);
    pk.z = bfpair(mz[4], mz[5]); pk.w = bfpair(mz[6], mz[7]);
    *(uint4*)(wrow + 192 + fb * 8) = pk;
  }
}

// one wave per node; contiguous clipped CSR range [lo,hi); row stride 320.
__global__ __launch_bounds__(256) void k_gather(
    const unsigned short* __restrict__ m_buf,
    const int* __restrict__ row_start,
    float* __restrict__ acc, int e0, int e1) {
  int g = threadIdx.x & 63;
  int wv = threadIdx.x >> 6;
  int n = blockIdx.x * 4 + wv;
  int beg = row_start[n], end = row_start[n + 1];
  int lo = beg > e0 ? beg : e0;
  int hi = end < e1 ? end : e1;
  if (lo >= hi) return;
  float4 a = make_float4(0.f, 0.f, 0.f, 0.f);
  for (int i = lo; i < hi; ++i) {
    uint2 m = *(const uint2*)(m_buf + (size_t)(i - e0) * 320 + g * 4);
    a.x += __uint_as_float(m.x << 16);
    a.y += __uint_as_float(m.x & 0xFFFF0000u);
    a.z += __uint_as_float(m.y << 16);
    a.w += __uint_as_float(m.y & 0xFFFF0000u);
  }
  float* dst = acc + (size_t)n * 256 + g * 4;
  float4 p = *(const float4*)dst;  // serialized chunks: RMW is safe
  *(float4*)dst = make_float4(a.x + p.x, a.y + p.y, a.z + p.z, a.w + p.w);
}

__global__ __launch_bounds__(256) void k_post(
    const float* __restrict__ nf, const float* __restrict__ acc,
    const float* __restrict__ Wdns, const float* __restrict__ Wdnv,
    const float* __restrict__ Wsks, const float* __restrict__ Wskv,
    const float* __restrict__ Wsc,
    const float* __restrict__ Wpss, const float* __restrict__ Wpsv,
    const float* __restrict__ Wout, const int* __restrict__ species,
    float* __restrict__ out) {
  __shared__ __align__(16) float xch[4][4][4][68];
  int g = threadIdx.x & 63;
  int wv = threadIdx.x >> 6;
  int n0 = (blockIdx.x * 4 + wv) * 4;
  int spec[4];
#pragma unroll
  for (int i = 0; i < 4; ++i) spec[i] = species[n0 + i];
  float s3[4] = {0, 0, 0, 0};
  float v3[4][3] = {{0,0,0},{0,0,0},{0,0,0},{0,0,0}};
  float sks[4] = {0, 0, 0, 0};
  float skv[4][3] = {{0,0,0},{0,0,0},{0,0,0},{0,0,0}};
  for (int fq = 0; fq < 16; ++fq) {
    int f = fq * 4;
    float d0 = Wdns[(f + 0) * 64 + g], d1 = Wdns[(f + 1) * 64 + g];
    float d2 = Wdns[(f + 2) * 64 + g], d3 = Wdns[(f + 3) * 64 + g];
    float e0 = Wdnv[(f + 0) * 64 + g], e1 = Wdnv[(f + 1) * 64 + g];
    float e2 = Wdnv[(f + 2) * 64 + g], e3 = Wdnv[(f + 3) * 64 + g];
#pragma unroll
    for (int i = 0; i < 4; ++i) {
      int n = n0 + i;
      const float* arow = acc + (size_t)n * 256;
      float4 sa = *(const float4*)(arow + f);
      float4 vx = *(const float4*)(arow + 64 + f);
      float4 vy = *(const float4*)(arow + 128 + f);
      float4 vz = *(const float4*)(arow + 192 + f);
      s3[i]    += sa.x * d0 + sa.y * d1 + sa.z * d2 + sa.w * d3;
      v3[i][0] += vx.x * e0 + vx.y * e1 + vx.z * e2 + vx.w * e3;
      v3[i][1] += vy.x * e0 + vy.y * e1 + vy.z * e2 + vy.w * e3;
      v3[i][2] += vz.x * e0 + vz.y * e1 + vz.z * e2 + vz.w * e3;
      const float* ksb = Wsks + spec[i] * 4096 + f * 64 + g;  // coalesced
      const float* kvb = Wskv + spec[i] * 4096 + f * 64 + g;
      float k0 = ksb[0], k1 = ksb[64], k2 = ksb[128], k3 = ksb[192];
      float q0 = kvb[0], q1 = kvb[64], q2 = kvb[128], q3 = kvb[192];
      const float* row = nf + (size_t)n * 256;
      float4 s04 = *(const float4*)(row + f);
      const float4* vr = (const float4*)(row + 64 + fq * 12);
      float4 va = vr[0], vb = vr[1], vc = vr[2];
      sks[i]    += s04.x * k0 + s04.y * k1 + s04.z * k2 + s04.w * k3;
      skv[i][0] += va.x * q0 + va.w * q1 + vb.z * q2 + vc.y * q3;
      skv[i][1] += va.y * q0 + vb.x * q1 + vb.w * q2 + vc.z * q3;
      skv[i][2] += va.z * q0 + vb.y * q1 + vc.x * q2 + vc.w * q3;
    }
  }
#pragma unroll
  for (int i = 0; i < 4; ++i) {
    float s = s3[i] * INV8;
    float vx = v3[i][0] * INV8, vy = v3[i][1] * INV8, vz = v3[i][2] * INV8;
    float vn2 = vx * vx + vy * vy + vz * vz;
    const float* wz = Wsc + spec[i] * 576 + g;
    float w0 = wz[0], w1 = wz[64], w2 = wz[128], w3 = wz[192], w4 = wz[256];
    float w5 = wz[320], w6 = wz[384], w7 = wz[448], w8 = wz[512];
    float s_o = w0 * s + w1 * s * s + w2 * vn2 + w3 * s * s * s + w4 * s * vn2;
    float vcm = w5 + w6 * s + w7 * s * s + w8 * vn2;
    xch[wv][i][0][g] = s_o;
    xch[wv][i][1][g] = vcm * vx;
    xch[wv][i][2][g] = vcm * vy;
    xch[wv][i][3][g] = vcm * vz;
  }
  __syncthreads();
  float s4[4] = {0, 0, 0, 0};
  float v4[4][3] = {{0,0,0},{0,0,0},{0,0,0},{0,0,0}};
  for (int fq = 0; fq < 16; ++fq) {
    int f = fq * 4;
    float p0 = Wpss[(f + 0) * 64 + g], p1 = Wpss[(f + 1) * 64 + g];
    float p2 = Wpss[(f + 2) * 64 + g], p3 = Wpss[(f + 3) * 64 + g];
    float q0 = Wpsv[(f + 0) * 64 + g], q1 = Wpsv[(f + 1) * 64 + g];
    float q2 = Wpsv[(f + 2) * 64 + g], q3 = Wpsv[(f + 3) * 64 + g];
#pragma unroll
    for (int i = 0; i < 4; ++i) {
      float4 so = *(const float4*)(&xch[wv][i][0][f]);
      float4 u0 = *(const float4*)(&xch[wv][i][1][f]);
      float4 u1 = *(const float4*)(&xch[wv][i][2][f]);
      float4 u2 = *(const float4*)(&xch[wv][i][3][f]);
      s4[i]    += so.x * p0 + so.y * p1 + so.z * p2 + so.w * p3;
      v4[i][0] += u0.x * q0 + u0.y * q1 + u0.z * q2 + u0.w * q3;
      v4[i][1] += u1.x * q0 + u1.y * q1 + u1.z * q2 + u1.w * q3;
      v4[i][2] += u2.x * q0 + u2.y * q1 + u2.z * q2 + u2.w * q3;
    }
  }
  float wo = Wout[g];
#pragma unroll
  for (int i = 0; i < 4; ++i) {
    int n = n0 + i;
    float sf = s4[i] * INV8 + sks[i] * INVZ;
    float fx = v4[i][0] * INV8 + skv[i][0] * INVZ;
    float fy = v4[i][1] * INV8 + skv[i][1] * INVZ;
    float fz = v4[i][2] * INV8 + skv[i][2] * INVZ;
    float* orow = out + NN + (size_t)n * 256;
    orow[g] = sf;
    orow[64 + g * 3 + 0] = fx;
    orow[64 + g * 3 + 1] = fy;
    orow[64 + g * 3 + 2] = fz;
    float tsum = sf * wo;
#pragma unroll
    for (int off = 32; off > 0; off >>= 1) tsum += __shfl_down(tsum, off);
    if (g == 0) out[n] = tsum * INV8;
  }
}

extern "C" void kernel_launch(void* const* d_in, const int* in_sizes, int n_in,
                              void* d_out, int out_size, void* d_ws, size_t ws_size,
                              hipStream_t stream) {
  (void)in_sizes; (void)n_in; (void)out_size; (void)ws_size;
  const float* vecs = (const float*)d_in[0];
  const float* nf   = (const float*)d_in[1];
  const float* re   = (const float*)d_in[2];
  const float* Wsks = (const float*)d_in[3];
  const float* Wskv = (const float*)d_in[4];
  const float* Wups = (const float*)d_in[5];
  const float* Wupv = (const float*)d_in[6];
  const float* W1   = (const float*)d_in[7];
  const float* W2   = (const float*)d_in[8];
  const float* W3   = (const float*)d_in[9];
  const float* W4   = (const float*)d_in[10];
  const float* Wdns = (const float*)d_in[11];
  const float* Wdnv = (const float*)d_in[12];
  const float* Wsc  = (const float*)d_in[13];
  const float* Wpss = (const float*)d_in[14];
  const float* Wpsv = (const float*)d_in[15];
  const float* Wout = (const float*)d_in[16];
  const int* species = (const int*)d_in[17];
  const int* snd     = (const int*)d_in[18];
  const int* rcv     = (const int*)d_in[19];

  float* ws = (float*)d_ws;
  unsigned short* s_up  = (unsigned short*)ws;              // N*64 f16
  unsigned short* v_up  = (unsigned short*)(ws + 1048576);  // N*192 f16
  float* acc   = ws + 4194304;                              // N*256 f32
  unsigned short* fragw = (unsigned short*)(ws + 12582912); // 30720 f16
  int* row_st  = (int*)(ws + 12599296);                     // 32769 (+pad)
  int* cursor  = (int*)(ws + 12632068);                     // 32768
  int* elist   = (int*)(ws + 12664836);                     // 262144
  unsigned short* wm = (unsigned short*)(ws + 12926980);    // EC*320 f16/bf16

  hipMemsetAsync(cursor, 0, NN * sizeof(int), stream);
  hipMemsetAsync(acc, 0, (size_t)NN * 256 * sizeof(float), stream);
  k_frag<<<15, 256, 0, stream>>>(W1, W2, W3, W4, fragw);
  k_hist<<<EE / 256, 256, 0, stream>>>(rcv, cursor);
  k_scan<<<1, 1024, 0, stream>>>(cursor, row_st, cursor);
  k_fill<<<EE / 256, 256, 0, stream>>>(rcv, cursor, elist);
  k_up<<<2048, 256, 0, stream>>>(nf, Wups, Wupv, s_up, v_up);
  for (int c = 0; c < 2; ++c) {
    k_mlp<<<EC / 128, 256, 0, stream>>>(re, elist, fragw, wm, c * EC);
    k_tp<<<EC / 64, 256, 0, stream>>>(vecs, s_up, v_up, snd, elist, wm, c * EC);
    k_gather<<<NN / 4, 256, 0, stream>>>(wm, row_st, acc, c * EC, (c + 1) * EC);
  }
  k_post<<<2048, 256, 0, stream>>>(nf, acc, Wdns, Wdnv, Wsks, Wskv, Wsc,
                                   Wpss, Wpsv, Wout, species, (float*)d_out);
}